// Round 3
// baseline (44.019 us; speedup 1.0000x reference)
//
#include <hip/hip_runtime.h>
#include <math.h>

#define B_TOT 32768
#define DIM   512
#define NS    100
#define NCOL  101
#define TB    128              // rows per block (8 waves x 16 rows)
#define NBLK  (B_TOT / TB)     // 256 blocks

// d_ws layout (floats): [0, 28672) = Wpack (57344 shorts); [28672, 28784) = base[112];
// [28800, 30848) = per-wave loss partials (2048)
#define BASE_OFF 28672
#define LPART_OFF 28800
#define NPACK (16 * 7 * 64)    // (kc, c, lane) fragments, 8 shorts each

typedef __attribute__((ext_vector_type(8))) short short8;   // 8 bf16 (4 VGPRs)
typedef __attribute__((ext_vector_type(4))) float f32x4;    // MFMA accumulator

// fp32 -> bf16 round-to-nearest-even, bit form
static __device__ __forceinline__ short f2bf(float f) {
    unsigned u = __builtin_bit_cast(unsigned, f);
    unsigned r = (u + 0x7FFFu + ((u >> 16) & 1u)) >> 16;
    return (short)r;
}

// Pack sampled W into per-lane B-fragment layout: frag (kc,c,lane) at wpack[((kc*7+c)*64+lane)*8]
// holds W_bf16[col = c*16 + (lane&15)][k = kc*32 + (lane>>4)*8 + 0..7]; cols >= 100 zero-padded.
// Also base[col] = biases[sid] - log(sq), -inf padded to 112.
__global__ __launch_bounds__(256)
void pack_kernel(const float* __restrict__ weights, const float* __restrict__ biases,
                 const int* __restrict__ sids, const float* __restrict__ sq,
                 short* __restrict__ wpack, float* __restrict__ base_g)
{
    const int tid = blockIdx.x * 256 + threadIdx.x;
    if (tid < 112)
        base_g[tid] = (tid < NS) ? biases[sids[tid]] - logf(sq[tid]) : -INFINITY;
    if (tid >= NPACK) return;
    const int kc = tid / 448, rem = tid % 448;
    const int c = rem >> 6, l = rem & 63;
    const int col = c * 16 + (l & 15);
    const int k   = kc * 32 + (l >> 4) * 8;
    short8 v = (short8){0, 0, 0, 0, 0, 0, 0, 0};
    if (col < NS) {
        const float* src = weights + (long)sids[col] * DIM + k;
        const float4 f0 = *(const float4*)src;
        const float4 f1 = *(const float4*)(src + 4);
        v[0] = f2bf(f0.x); v[1] = f2bf(f0.y); v[2] = f2bf(f0.z); v[3] = f2bf(f0.w);
        v[4] = f2bf(f1.x); v[5] = f2bf(f1.y); v[6] = f2bf(f1.z); v[7] = f2bf(f1.w);
    }
    *(short8*)&wpack[(long)tid * 8] = v;
}

// Fused logits + LSE: zero LDS, zero barriers.
__global__ __launch_bounds__(512, 4)
void fused_kernel(const int* __restrict__ label,
                  const float* __restrict__ inputs,
                  const float* __restrict__ weights,
                  const float* __restrict__ biases,
                  const float* __restrict__ tq,
                  const short* __restrict__ wpack,
                  const float* __restrict__ base_g,
                  float* __restrict__ out,
                  float* __restrict__ lpart)
{
    const int t    = threadIdx.x;
    const int wave = t >> 6;
    const int lane = t & 63;
    const int rit  = lane & 15;              // A row within 16-row tile / C-D col index
    const int seg  = lane >> 4;              // k-segment (8 k each)
    const int absRow = blockIdx.x * TB + wave * 16 + rit;
    const int lab = label[absRow];
    const float* aptr = inputs  + (long)absRow * DIM + seg * 8;
    const float* wtp  = weights + (long)lab    * DIM + seg * 8;

    // hoist epilogue bases (L2 scalar-ish loads)
    float base_v[7];
    #pragma unroll
    for (int c = 0; c < 7; c++) base_v[c] = base_g[c * 16 + rit];

    f32x4 acc[7];
    #pragma unroll
    for (int c = 0; c < 7; c++) acc[c] = (f32x4){0.f, 0.f, 0.f, 0.f};
    float tacc = 0.f;

    // barrier-free K loop: A + true-W direct from global (fp32), B-frags from packed global (bf16)
    #pragma unroll
    for (int kc = 0; kc < DIM / 32; kc++) {
        const int k0 = kc * 32;
        const float4 a0 = *(const float4*)(aptr + k0);
        const float4 a1 = *(const float4*)(aptr + k0 + 4);
        const float4 w0 = *(const float4*)(wtp + k0);
        const float4 w1 = *(const float4*)(wtp + k0 + 4);

        tacc = fmaf(a0.x, w0.x, tacc); tacc = fmaf(a0.y, w0.y, tacc);
        tacc = fmaf(a0.z, w0.z, tacc); tacc = fmaf(a0.w, w0.w, tacc);
        tacc = fmaf(a1.x, w1.x, tacc); tacc = fmaf(a1.y, w1.y, tacc);
        tacc = fmaf(a1.z, w1.z, tacc); tacc = fmaf(a1.w, w1.w, tacc);

        short8 af;
        af[0] = f2bf(a0.x); af[1] = f2bf(a0.y); af[2] = f2bf(a0.z); af[3] = f2bf(a0.w);
        af[4] = f2bf(a1.x); af[5] = f2bf(a1.y); af[6] = f2bf(a1.z); af[7] = f2bf(a1.w);

        const short* wp = wpack + ((long)kc * 7 * 64 + lane) * 8;
        #pragma unroll
        for (int c = 0; c < 7; c++) {
            const short8 bf = *(const short8*)(wp + c * 64 * 8);
            acc[c] = __builtin_amdgcn_mfma_f32_16x16x32_bf16(af, bf, acc[c], 0, 0, 0);
        }
    }

    // true logit: reduce the 4 k-segments; every lane ends with tl for row (lane&15)
    tacc += __shfl_xor(tacc, 16);
    tacc += __shfl_xor(tacc, 32);
    const float tl = tacc + biases[lab] - logf(tq[absRow]);
    if (lane < 16) out[(long)absRow * NCOL] = tl;

    // fused per-row LSE + loss + sampled-logit writes
    // C/D layout: col = lane&15 (rit), row = (lane>>4)*4 + reg
    const int g = lane >> 4;
    float loss_sum = 0.f;
    #pragma unroll
    for (int i = 0; i < 4; i++) {
        const int r = g * 4 + i;
        const long orow = (long)(blockIdx.x * TB + wave * 16 + r) * NCOL;
        const float tlv = __shfl(tl, r);     // lane r holds row r's true logit
        float v[7];
        float m = tlv;
        #pragma unroll
        for (int c = 0; c < 7; c++) {
            v[c] = acc[c][i] + base_v[c];    // base = -inf for pad cols -> v = -inf
            m = fmaxf(m, v[c]);
        }
        #pragma unroll
        for (int off = 1; off < 16; off <<= 1) m = fmaxf(m, __shfl_xor(m, off));
        float s = (rit == 0) ? expf(tlv - m) : 0.f;
        #pragma unroll
        for (int c = 0; c < 7; c++) s += expf(v[c] - m);
        #pragma unroll
        for (int off = 1; off < 16; off <<= 1) s += __shfl_xor(s, off);
        loss_sum += m + logf(s) - tlv;
        #pragma unroll
        for (int c = 0; c < 7; c++) {
            const int col = c * 16 + rit;
            if (col < NS) out[orow + 1 + col] = v[c];
        }
    }
    float wl = (rit == 0) ? loss_sum : 0.f;
    wl += __shfl_xor(wl, 16);
    wl += __shfl_xor(wl, 32);
    if (lane == 0) lpart[blockIdx.x * 8 + wave] = wl;
}

// deterministic tree reduce of 2048 per-wave partials in double -> mean loss
__global__ __launch_bounds__(256)
void reduce_kernel(const float* __restrict__ lpart, float* __restrict__ out_loss)
{
    double s = 0.0;
    for (int i = threadIdx.x; i < NBLK * 8; i += 256) s += (double)lpart[i];
    __shared__ double buf[256];
    buf[threadIdx.x] = s;
    __syncthreads();
    for (int o = 128; o > 0; o >>= 1) {
        if (threadIdx.x < o) buf[threadIdx.x] += buf[threadIdx.x + o];
        __syncthreads();
    }
    if (threadIdx.x == 0) *out_loss = (float)(buf[0] * (1.0 / (double)B_TOT));
}

extern "C" void kernel_launch(void* const* d_in, const int* in_sizes, int n_in,
                              void* d_out, int out_size, void* d_ws, size_t ws_size,
                              hipStream_t stream)
{
    const int*   label   = (const int*)d_in[0];
    const float* inputs  = (const float*)d_in[1];
    const float* weights = (const float*)d_in[2];
    const float* biases  = (const float*)d_in[3];
    const int*   sids    = (const int*)d_in[4];
    const float* tq      = (const float*)d_in[5];
    const float* sq      = (const float*)d_in[6];
    float* out  = (float*)d_out;
    float* ws_f = (float*)d_ws;
    short* wpack  = (short*)d_ws;
    float* base_g = ws_f + BASE_OFF;
    float* lpart  = ws_f + LPART_OFF;

    pack_kernel<<<28, 256, 0, stream>>>(weights, biases, sids, sq, wpack, base_g);
    fused_kernel<<<NBLK, 512, 0, stream>>>(label, inputs, weights, biases, tq,
                                           wpack, base_g, out, lpart);
    reduce_kernel<<<1, 256, 0, stream>>>(lpart, out + (long)B_TOT * NCOL);
}

// Round 4
// 41.405 us; speedup vs baseline: 1.0631x; 1.0631x over previous
//
#include <hip/hip_runtime.h>
#include <math.h>

#define B_TOT 32768
#define DIM   512
#define NS    100
#define NCOL  101
#define TB    128              // rows per block (8 row-groups x 16 rows)
#define NBLK  (B_TOT / TB)     // 256 blocks
#define NPACK (16 * 7 * 64)    // (kc, c, lane) fragments, 8 shorts each

// d_ws layout (floats): [0, 28672) = Wpack (57344 shorts); [28672, 28784) = base[112];
// [28800, 29056) = per-block loss partials
#define BASE_OFF 28672
#define LPART_OFF 28800

typedef __attribute__((ext_vector_type(8))) short short8;   // 8 bf16 (4 VGPRs)
typedef __attribute__((ext_vector_type(4))) float f32x4;    // MFMA accumulator

// fp32 -> bf16 round-to-nearest-even, bit form
static __device__ __forceinline__ short f2bf(float f) {
    unsigned u = __builtin_bit_cast(unsigned, f);
    unsigned r = (u + 0x7FFFu + ((u >> 16) & 1u)) >> 16;
    return (short)r;
}

// Pack sampled W into per-lane B-fragment layout: frag (kc,c,lane) at wpack[((kc*7+c)*64+lane)*8]
// holds W_bf16[col = c*16 + (lane&15)][k = kc*32 + (lane>>4)*8 + 0..7]; cols >= 100 zero-padded.
__global__ __launch_bounds__(256)
void pack_kernel(const float* __restrict__ weights, const float* __restrict__ biases,
                 const int* __restrict__ sids, const float* __restrict__ sq,
                 short* __restrict__ wpack, float* __restrict__ base_g)
{
    const int tid = blockIdx.x * 256 + threadIdx.x;
    if (tid < 112)
        base_g[tid] = (tid < NS) ? biases[sids[tid]] - logf(sq[tid]) : -INFINITY;
    if (tid >= NPACK) return;
    const int kc = tid / 448, rem = tid % 448;
    const int c = rem >> 6, l = rem & 63;
    const int col = c * 16 + (l & 15);
    const int k   = kc * 32 + (l >> 4) * 8;
    short8 v = (short8){0, 0, 0, 0, 0, 0, 0, 0};
    if (col < NS) {
        const float* src = weights + (long)sids[col] * DIM + k;
        const float4 f0 = *(const float4*)src;
        const float4 f1 = *(const float4*)(src + 4);
        v[0] = f2bf(f0.x); v[1] = f2bf(f0.y); v[2] = f2bf(f0.z); v[3] = f2bf(f0.w);
        v[4] = f2bf(f1.x); v[5] = f2bf(f1.y); v[6] = f2bf(f1.z); v[7] = f2bf(f1.w);
    }
    *(short8*)&wpack[(long)tid * 8] = v;
}

// Fused logits + LSE. 16 waves/block = 8 row-groups x 2 K-halves; B-frags from LDS (lgkmcnt),
// only A-stream + true-row gather on vmcnt.
__global__ __launch_bounds__(1024, 4)
void fused_kernel(const int* __restrict__ label,
                  const float* __restrict__ inputs,
                  const float* __restrict__ weights,
                  const float* __restrict__ biases,
                  const float* __restrict__ tq,
                  const short* __restrict__ wpack,
                  const float* __restrict__ base_g,
                  float* __restrict__ out,
                  float* __restrict__ lpart)
{
    __shared__ short W_lds[NPACK * 8];      // 114688 B, exact wpack layout
    __shared__ float tl_x[TB];              // odd-half true-dot partials
    __shared__ float ls_lds[8];             // per-row-group loss partials

    const int t = threadIdx.x;

    // ---- stage wpack -> LDS, fully coalesced (7 x short8 per thread) ----
    {
        const short8* src = (const short8*)wpack;
        short8* dst = (short8*)W_lds;
        #pragma unroll
        for (int s = 0; s < 7; s++)
            dst[s * 1024 + t] = src[s * 1024 + t];
    }

    const int wave = t >> 6;
    const int lane = t & 63;
    const int rg   = wave >> 1;              // row-group 0..7
    const int kh   = wave & 1;               // K half (256 each)
    const int rit  = lane & 15;              // A row within tile / C-D col index
    const int seg  = lane >> 4;              // k-segment (8 k each)
    const int absRow = blockIdx.x * TB + rg * 16 + rit;
    const int lab = label[absRow];
    const float* aptr = inputs  + (long)absRow * DIM + kh * 256 + seg * 8;
    const float* wtp  = weights + (long)lab    * DIM + kh * 256 + seg * 8;

    f32x4 acc[7];
    #pragma unroll
    for (int c = 0; c < 7; c++) acc[c] = (f32x4){0.f, 0.f, 0.f, 0.f};
    float tacc = 0.f;

    __syncthreads();

    // ---- K-half loop: A + true-W from global (vmcnt), B-frags ds_read_b128 (lgkmcnt) ----
    #pragma unroll
    for (int kc = 0; kc < 8; kc++) {
        const int k0 = kc * 32;
        const float4 a0 = *(const float4*)(aptr + k0);
        const float4 a1 = *(const float4*)(aptr + k0 + 4);
        const float4 w0 = *(const float4*)(wtp + k0);
        const float4 w1 = *(const float4*)(wtp + k0 + 4);

        tacc = fmaf(a0.x, w0.x, tacc); tacc = fmaf(a0.y, w0.y, tacc);
        tacc = fmaf(a0.z, w0.z, tacc); tacc = fmaf(a0.w, w0.w, tacc);
        tacc = fmaf(a1.x, w1.x, tacc); tacc = fmaf(a1.y, w1.y, tacc);
        tacc = fmaf(a1.z, w1.z, tacc); tacc = fmaf(a1.w, w1.w, tacc);

        short8 af;
        af[0] = f2bf(a0.x); af[1] = f2bf(a0.y); af[2] = f2bf(a0.z); af[3] = f2bf(a0.w);
        af[4] = f2bf(a1.x); af[5] = f2bf(a1.y); af[6] = f2bf(a1.z); af[7] = f2bf(a1.w);

        const int kcg = kh * 8 + kc;
        const short* wp = &W_lds[((kcg * 7) * 64 + lane) * 8];
        #pragma unroll
        for (int c = 0; c < 7; c++) {
            const short8 bf = *(const short8*)(wp + c * 64 * 8);
            acc[c] = __builtin_amdgcn_mfma_f32_16x16x32_bf16(af, bf, acc[c], 0, 0, 0);
        }
    }

    // per-half true-dot: reduce 4 k-segments; all lanes get row rit's half value
    tacc += __shfl_xor(tacc, 16);
    tacc += __shfl_xor(tacc, 32);

    __syncthreads();   // all waves done reading W_lds; reuse it as exchange buffer

    float* ex = (float*)W_lds;   // pitch 29 floats/lane: coprime with 32 banks
    if (kh == 1) {
        const int base = rg * 1856 + lane * 29;
        #pragma unroll
        for (int c = 0; c < 7; c++)
            #pragma unroll
            for (int i = 0; i < 4; i++)
                ex[base + c * 4 + i] = acc[c][i];
        if (lane < 16) tl_x[rg * 16 + lane] = tacc;
    }
    __syncthreads();

    if (kh == 0) {
        const int base = rg * 1856 + lane * 29;
        #pragma unroll
        for (int c = 0; c < 7; c++)
            #pragma unroll
            for (int i = 0; i < 4; i++)
                acc[c][i] += ex[base + c * 4 + i];
        tacc += tl_x[rg * 16 + rit];

        float base_v[7];
        #pragma unroll
        for (int c = 0; c < 7; c++) base_v[c] = base_g[c * 16 + rit];

        const float tl = tacc + biases[lab] - logf(tq[absRow]);
        if (lane < 16) out[(long)absRow * NCOL] = tl;

        // fused per-row LSE + loss + sampled-logit writes
        // C/D layout: col = lane&15 (rit), row = (lane>>4)*4 + reg
        const int g = lane >> 4;
        float loss_sum = 0.f;
        #pragma unroll
        for (int i = 0; i < 4; i++) {
            const int r = g * 4 + i;
            const long orow = (long)(blockIdx.x * TB + rg * 16 + r) * NCOL;
            const float tlv = __shfl(tl, r);     // lane r holds row r's true logit
            float v[7];
            float m = tlv;
            #pragma unroll
            for (int c = 0; c < 7; c++) {
                v[c] = acc[c][i] + base_v[c];    // base = -inf for pad cols
                m = fmaxf(m, v[c]);
            }
            #pragma unroll
            for (int off = 1; off < 16; off <<= 1) m = fmaxf(m, __shfl_xor(m, off));
            float s = (rit == 0) ? expf(tlv - m) : 0.f;
            #pragma unroll
            for (int c = 0; c < 7; c++) s += expf(v[c] - m);
            #pragma unroll
            for (int off = 1; off < 16; off <<= 1) s += __shfl_xor(s, off);
            loss_sum += m + logf(s) - tlv;
            #pragma unroll
            for (int c = 0; c < 7; c++) {
                const int col = c * 16 + rit;
                if (col < NS) out[orow + 1 + col] = v[c];
            }
        }
        float wl = (rit == 0) ? loss_sum : 0.f;
        wl += __shfl_xor(wl, 16);
        wl += __shfl_xor(wl, 32);
        if (lane == 0) ls_lds[rg] = wl;
    }
    __syncthreads();
    if (t == 0) {
        float bp = 0.f;
        #pragma unroll
        for (int w = 0; w < 8; w++) bp += ls_lds[w];
        lpart[blockIdx.x] = bp;
    }
}

// deterministic tree reduce of 256 block partials in double -> mean loss
__global__ __launch_bounds__(256)
void reduce_kernel(const float* __restrict__ lpart, float* __restrict__ out_loss)
{
    __shared__ double buf[256];
    buf[threadIdx.x] = (double)lpart[threadIdx.x];
    __syncthreads();
    for (int o = 128; o > 0; o >>= 1) {
        if (threadIdx.x < o) buf[threadIdx.x] += buf[threadIdx.x + o];
        __syncthreads();
    }
    if (threadIdx.x == 0) *out_loss = (float)(buf[0] * (1.0 / (double)B_TOT));
}

extern "C" void kernel_launch(void* const* d_in, const int* in_sizes, int n_in,
                              void* d_out, int out_size, void* d_ws, size_t ws_size,
                              hipStream_t stream)
{
    const int*   label   = (const int*)d_in[0];
    const float* inputs  = (const float*)d_in[1];
    const float* weights = (const float*)d_in[2];
    const float* biases  = (const float*)d_in[3];
    const int*   sids    = (const int*)d_in[4];
    const float* tq      = (const float*)d_in[5];
    const float* sq      = (const float*)d_in[6];
    float* out  = (float*)d_out;
    float* ws_f = (float*)d_ws;
    short* wpack  = (short*)d_ws;
    float* base_g = ws_f + BASE_OFF;
    float* lpart  = ws_f + LPART_OFF;

    pack_kernel<<<28, 256, 0, stream>>>(weights, biases, sids, sq, wpack, base_g);
    fused_kernel<<<NBLK, 1024, 0, stream>>>(label, inputs, weights, biases, tq,
                                            wpack, base_g, out, lpart);
    reduce_kernel<<<1, 256, 0, stream>>>(lpart, out + (long)B_TOT * NCOL);
}